// Round 10
// baseline (1493.918 us; speedup 1.0000x reference)
//
#include <hip/hip_runtime.h>
#include <math.h>

// SGC: out = log_softmax((A_hat^2 x) W + b), A_hat = D^-1/2 (A+I) D^-1/2
// (A^2 X) W == A^2 (X W): propagate in 40-dim class space.
// Z buffers bf16, 128B-padded rows; MFMA split-bf16 gemm; 2-team pull prop
// (8-wide pipelined gathers).
// Round-18: FULL FUSION -- all 7 kernels -> ONE dispatch. Evidence: four
// consecutive prop-MLP rounds gained <2% each (prop is at a request-
// throughput floor); per-kernel floors sum to ~130-150us vs 212 measured;
// the residual is the 6 inter-kernel boundaries (full-grid drain+dispatch).
// Bodies are round-9 VERBATIM; phases separated by a monotonic global
// atomic-counter barrier (device-scope atomics + threadfence; all 1024
// blocks co-resident BY CONSTRUCTION: launch_bounds(256,4) caps VGPR at
// 128 -> 4 waves/EU, LDS union 13.3KB*4=53KB<160KB, 16 waves/CU<32).
// Grid-stride for gemm (1563 tiles) & prop (4000 node-blocks); build
// phases run on blocks <512; wprep on block 1023 parallel with hist.
// ctr zeroed via hipMemsetAsync (graph-capturable). Falsification: if
// this REGRESSES >10us, prop was occupancy-sensitive -> split props out.

#define FDIM 128
#define CDIM 40
#define BKT_SHIFT 8
#define NB   512   // bucket slots (>= ceil(N/256))
#define NBLK 512   // edge-partition blocks
#define NPB  25    // nodes per prop block-task (10 lanes/node, 2 teams)
#define ZSTR 8     // Z row stride in uint4 (128 B; 5 used, 3 pad)
#define EPS  52    // gemm epilogue LDS row stride (floats)
#define GRID 1024  // fused grid: 4 blocks/CU on 256 CUs

typedef __attribute__((ext_vector_type(4))) float floatx4;
typedef __attribute__((ext_vector_type(8))) short bshort8;

union Smem {
    int h[NB];                                                  // hist
    int cs[256];                                                // colscan
    struct { int bsl[NB + 1]; int lds[256]; int offs[NB]; int cur[NB]; } part;
    struct { int bsl[NB + 1]; int lds[256]; int cnt[256]; int ptr[256]; } csr;
    float ep[64 * EPS];                                         // gemm, 13.3 KB
    struct { float bsm[CDIM]; float red[256]; float pr[NPB * 5 * 8]; } prop;
};

// ---------- bf16 helpers (RTNE pack; finite inputs) ----------
__device__ __forceinline__ unsigned int bf16rn(float f) {
    unsigned int u = __float_as_uint(f);
    return (u + 0x7fffu + ((u >> 16) & 1u)) >> 16;
}
__device__ __forceinline__ unsigned int pack2(float lo, float hi) {
    unsigned int a = bf16rn(lo);
    unsigned int b = __float_as_uint(hi);
    b = (b + 0x7fffu + ((b >> 16) & 1u)) & 0xffff0000u;
    return a | b;
}
__device__ __forceinline__ void addu4(uint4 u, float* a) {
    a[0] += __uint_as_float(u.x << 16);
    a[1] += __uint_as_float(u.x & 0xffff0000u);
    a[2] += __uint_as_float(u.y << 16);
    a[3] += __uint_as_float(u.y & 0xffff0000u);
    a[4] += __uint_as_float(u.z << 16);
    a[5] += __uint_as_float(u.z & 0xffff0000u);
    a[6] += __uint_as_float(u.w << 16);
    a[7] += __uint_as_float(u.w & 0xffff0000u);
}
__device__ __forceinline__ void split8(const float* p, bshort8& hi, bshort8& lo) {
    float4 a = *(const float4*)p;
    float4 b = *(const float4*)(p + 4);
    float f[8] = {a.x, a.y, a.z, a.w, b.x, b.y, b.z, b.w};
    #pragma unroll
    for (int j = 0; j < 8; ++j) {
        unsigned int u = __float_as_uint(f[j]);
        float r = f[j] - __uint_as_float(u & 0xffff0000u);
        hi[j] = (short)(u >> 16);
        lo[j] = (short)(__float_as_uint(r) >> 16);
    }
}

// ---- grid barrier: monotonic counter, device-scope. All GRID blocks are
// co-resident (see launch_bounds math above), so spinning is safe.
__device__ __forceinline__ void gsync(int* ctr, int target) {
    __syncthreads();
    if (threadIdx.x == 0) {
        __threadfence();   // release: my writes visible device-wide
        __hip_atomic_fetch_add(ctr, 1, __ATOMIC_RELEASE, __HIP_MEMORY_SCOPE_AGENT);
        while (__hip_atomic_load(ctr, __ATOMIC_ACQUIRE, __HIP_MEMORY_SCOPE_AGENT) < target)
            __builtin_amdgcn_s_sleep(2);
        __threadfence();   // acquire: remote writes visible to my block
    }
    __syncthreads();
}

// ---- inline exclusive scan of T[0..NB) into bsl[0..NB] (bsl[NB]=total).
__device__ __forceinline__ void scanT(const int* __restrict__ T, int* bsl,
                                      int* lds, int t) {
    int v0 = T[2 * t];
    int v1 = T[2 * t + 1];
    int s = v0 + v1;
    lds[t] = s;
    __syncthreads();
    for (int off = 1; off < 256; off <<= 1) {
        int a = (t >= off) ? lds[t - off] : 0;
        __syncthreads();
        lds[t] += a;
        __syncthreads();
    }
    int excl = lds[t] - s;
    bsl[2 * t] = excl;
    bsl[2 * t + 1] = excl + v0;
    if (t == 255) bsl[NB] = lds[255];
    __syncthreads();
}

// ---- prop hop body (round-9 verbatim; returns removed for fusion).
template <bool FINAL>
__device__ __forceinline__ void prop_body(Smem& sm, int pb,
    const int* __restrict__ rowptr, const int* __restrict__ col,
    const float* __restrict__ dinv, const float* __restrict__ dsq,
    const float* __restrict__ bias, const uint4* __restrict__ Zin,
    uint4* __restrict__ Zout_bf, float* __restrict__ out_f32, int n) {
    int t = threadIdx.x;
    if (FINAL && t < CDIM) sm.prop.bsm[t] = bias[t];
    int g = t / 10;
    int r = t - g * 10;
    int team = r / 5;           // 0 or 1
    int c8 = r - team * 5;      // 0..4
    int node = pb * NPB + g;
    bool active = (g < NPB) && (node < n);
    float acc[8];
    #pragma unroll
    for (int c = 0; c < 8; ++c) acc[c] = 0.f;
    float w = 0.f;
    if (active) {
        float di = dinv[node];
        w = di * di;
        if (team == 0) addu4(Zin[(size_t)node * ZSTR + c8], acc);   // self-loop
        int end = rowptr[node + 1];
        int end1 = end - 1;
        int e0 = rowptr[node] + team * 8;
        if (e0 < end) {
            int sv[8];
            #pragma unroll
            for (int k = 0; k < 8; ++k)
                sv[k] = col[min(e0 + k, end1)];     // preload iter 0
            for (int base = e0; base < end; base += 16) {
                uint4 av[8];
                #pragma unroll
                for (int k = 0; k < 8; ++k)
                    av[k] = Zin[(size_t)sv[k] * ZSTR + c8];  // 8 in flight
                #pragma unroll
                for (int k = 0; k < 8; ++k)
                    sv[k] = col[min(base + 16 + k, end1)];   // prefetch next
                #pragma unroll
                for (int k = 0; k < 8; ++k) {
                    if (base + k >= end) av[k] = make_uint4(0u, 0u, 0u, 0u);
                    addu4(av[k], acc);
                }
            }
        }
    }
    // merge team-1 partials into team-0 accumulators.
    if (active && team == 1) {
        float* p = &sm.prop.pr[(g * 5 + c8) * 8];
        #pragma unroll
        for (int j = 0; j < 8; ++j) p[j] = acc[j];
    }
    __syncthreads();   // also publishes bsm for FINAL
    if (active && team == 0) {
        const float* p = &sm.prop.pr[(g * 5 + c8) * 8];
        #pragma unroll
        for (int j = 0; j < 8; ++j) acc[j] += p[j];
    }

    if (!FINAL) {
        if (active && team == 0) {
            uint4 o;
            o.x = pack2(acc[0] * w, acc[1] * w);
            o.y = pack2(acc[2] * w, acc[3] * w);
            o.z = pack2(acc[4] * w, acc[5] * w);
            o.w = pack2(acc[6] * w, acc[7] * w);
            Zout_bf[(size_t)node * ZSTR + c8] = o;
        }
    } else {
        float v[8];
        float m8 = -INFINITY;
        if (active && team == 0) {
            float ws_ = w * dsq[node];
            #pragma unroll
            for (int j = 0; j < 8; ++j) {
                v[j] = acc[j] * ws_ + sm.prop.bsm[c8 * 8 + j];
                m8 = fmaxf(m8, v[j]);
            }
        }
        sm.prop.red[t] = m8;
        __syncthreads();
        float m = m8;
        if (active && team == 0) {
            int rb = g * 10;
            m = fmaxf(fmaxf(fmaxf(sm.prop.red[rb], sm.prop.red[rb + 1]),
                            fmaxf(sm.prop.red[rb + 2], sm.prop.red[rb + 3])),
                      sm.prop.red[rb + 4]);
        }
        float s8 = 0.f;
        if (active && team == 0) {
            #pragma unroll
            for (int j = 0; j < 8; ++j) s8 += expf(v[j] - m);
        }
        __syncthreads();
        sm.prop.red[t] = s8;
        __syncthreads();
        if (active && team == 0) {
            int rb = g * 10;
            float s = (sm.prop.red[rb] + sm.prop.red[rb + 1]) +
                      (sm.prop.red[rb + 2] + sm.prop.red[rb + 3]) + sm.prop.red[rb + 4];
            float ls = m + logf(s);
            float* p = out_f32 + (size_t)node * CDIM + c8 * 8;
            *(float4*)p = make_float4(v[0] - ls, v[1] - ls, v[2] - ls, v[3] - ls);
            *(float4*)(p + 4) = make_float4(v[4] - ls, v[5] - ls, v[6] - ls, v[7] - ls);
        }
    }
}

// ---- the whole pipeline in one dispatch.
__global__ __launch_bounds__(256, 4) void fused_k(
    const int* __restrict__ src, const int* __restrict__ dst,
    const float* __restrict__ x, const float* __restrict__ W,
    const float* __restrict__ bias,
    int* __restrict__ G, int* __restrict__ T, unsigned int* __restrict__ tmp,
    int* __restrict__ rowptr, float* __restrict__ dinv, float* __restrict__ dsq,
    int* __restrict__ col, uint4* __restrict__ WF,
    uint4* __restrict__ Z0, uint4* __restrict__ Zb, float* __restrict__ out,
    int* __restrict__ ctr, int N, int E, int EB) {
    __shared__ Smem sm;
    int t = threadIdx.x;
    int bid = blockIdx.x;

    // ---- P0: hist (blocks 0..511) | wprep (block 1023) ----
    if (bid < NBLK) {
        for (int i = t; i < NB; i += 256) sm.h[i] = 0;
        __syncthreads();
        int s = bid * EB;
        int e = min(s + EB, E);
        for (int i = s + t; i < e; i += 256)
            atomicAdd(&sm.h[dst[i] >> BKT_SHIFT], 1);
        __syncthreads();
        for (int i = t; i < NB; i += 256) G[bid * NB + i] = sm.h[i];
    } else if (bid == GRID - 1) {
        // wprep: split-bf16 W -> MFMA B-fragment order (lane l holds
        // B[k=8*(l>>4)+j][n=l&15]; g = nt*4+ch; hi WF[g*64+l], lo +768).
        for (int s = t; s < 768; s += 256) {
            int l = s & 63;
            int g = s >> 6;
            int nt = g >> 2;
            int ch = g & 3;
            int c = nt * 16 + (l & 15);
            int kb = ch * 32 + ((l >> 4) << 3);
            unsigned int hw[4], lw[4];
            #pragma unroll
            for (int jw = 0; jw < 4; ++jw) {
                unsigned int hs[2], ls[2];
                #pragma unroll
                for (int e2 = 0; e2 < 2; ++e2) {
                    int j = jw * 2 + e2;
                    float w = (c < CDIM) ? W[(kb + j) * CDIM + c] : 0.f;
                    unsigned int u = __float_as_uint(w);
                    float wh = __uint_as_float(u & 0xffff0000u);
                    float wr = w - wh;
                    hs[e2] = u >> 16;
                    ls[e2] = __float_as_uint(wr) >> 16;
                }
                hw[jw] = hs[0] | (hs[1] << 16);
                lw[jw] = ls[0] | (ls[1] << 16);
            }
            WF[g * 64 + l] = make_uint4(hw[0], hw[1], hw[2], hw[3]);
            WF[768 + g * 64 + l] = make_uint4(lw[0], lw[1], lw[2], lw[3]);
        }
    }
    gsync(ctr, GRID);

    // ---- P1: colscan (blocks 0..511) ----
    if (bid < NB) {
        int j = bid;
        int v0 = G[(2 * t) * NB + j];
        int v1 = G[(2 * t + 1) * NB + j];
        int s = v0 + v1;
        sm.cs[t] = s;
        __syncthreads();
        for (int off = 1; off < 256; off <<= 1) {
            int a = (t >= off) ? sm.cs[t - off] : 0;
            __syncthreads();
            sm.cs[t] += a;
            __syncthreads();
        }
        int excl = sm.cs[t] - s;
        G[(2 * t) * NB + j] = excl;
        G[(2 * t + 1) * NB + j] = excl + v0;
        if (t == 255) T[j] = sm.cs[255];
    }
    gsync(ctr, 2 * GRID);

    // ---- P2: part (blocks 0..511) ----
    if (bid < NBLK) {
        scanT(T, sm.part.bsl, sm.part.lds, t);
        for (int i = t; i < NB; i += 256) {
            sm.part.offs[i] = sm.part.bsl[i] + G[bid * NB + i];
            sm.part.cur[i] = 0;
        }
        __syncthreads();
        int s = bid * EB;
        int e = min(s + EB, E);
        for (int i = s + t; i < e; i += 256) {
            int d = dst[i];
            int j = d >> BKT_SHIFT;
            int r = atomicAdd(&sm.part.cur[j], 1);
            tmp[sm.part.offs[j] + r] =
                (unsigned int)src[i] | ((unsigned int)(d & 255) << 24);
        }
    }
    gsync(ctr, 3 * GRID);

    // ---- P3: csr (blocks 0..NBr-1) ----
    int NBr = (N + 255) >> BKT_SHIFT;
    if (bid < NBr) {
        scanT(T, sm.csr.bsl, sm.csr.lds, t);
        int j = bid;
        int base = j << BKT_SHIFT;
        int s = sm.csr.bsl[j];
        int e = sm.csr.bsl[j + 1];
        sm.csr.cnt[t] = 0;
        __syncthreads();
        for (int i = s + t; i < e; i += 256)
            atomicAdd(&sm.csr.cnt[tmp[i] >> 24], 1);
        __syncthreads();
        int v = sm.csr.cnt[t];
        sm.csr.ptr[t] = v;
        __syncthreads();
        for (int off = 1; off < 256; off <<= 1) {
            int a = (t >= off) ? sm.csr.ptr[t - off] : 0;
            __syncthreads();
            sm.csr.ptr[t] += a;
            __syncthreads();
        }
        int excl = sm.csr.ptr[t] - v;
        int node = base + t;
        if (node < N) {
            rowptr[node] = s + excl;
            float d = (float)(v + 1);          // +1 self-loop
            dinv[node] = rsqrtf(d);
            dsq[node] = sqrtf(d);
        }
        if (j == 0 && t == 0) rowptr[N] = E;
        sm.csr.cnt[t] = excl;  // cursor
        __syncthreads();
        for (int i = s + t; i < e; i += 256) {
            unsigned int p = tmp[i];
            int loc = p >> 24;
            int r = atomicAdd(&sm.csr.cnt[loc], 1);
            col[s + r] = (int)(p & 0xFFFFFF);
        }
    }
    gsync(ctr, 4 * GRID);

    // ---- P4: gemm (grid-stride over 64-node tiles) ----
    {
        int wid = t >> 6;
        int l = t & 63;
        int lr = l & 15;
        int lg = l >> 4;
        const bshort8* WFv = (const bshort8*)WF;
        int ntile = (N + 63) / 64;
        for (int blk = bid; blk < ntile; blk += GRID) {
            __syncthreads();   // LDS ep reuse across iterations
            int base64 = blk * 64;
            int mbase = base64 + wid * 16;
            int node_a = mbase + lr;
            bool arow_ok = node_a < N;
            floatx4 acc0 = {0.f, 0.f, 0.f, 0.f};
            floatx4 acc1 = {0.f, 0.f, 0.f, 0.f};
            floatx4 acc2 = {0.f, 0.f, 0.f, 0.f};
            #pragma unroll
            for (int ch = 0; ch < 4; ++ch) {
                bshort8 ah, al;
                if (arow_ok) {
                    split8(x + (size_t)node_a * FDIM + ch * 32 + lg * 8, ah, al);
                } else {
                    #pragma unroll
                    for (int j = 0; j < 8; ++j) { ah[j] = 0; al[j] = 0; }
                }
                bshort8 bh0 = WFv[(0 * 4 + ch) * 64 + l];
                bshort8 bl0 = WFv[768 + (0 * 4 + ch) * 64 + l];
                bshort8 bh1 = WFv[(1 * 4 + ch) * 64 + l];
                bshort8 bl1 = WFv[768 + (1 * 4 + ch) * 64 + l];
                bshort8 bh2 = WFv[(2 * 4 + ch) * 64 + l];
                bshort8 bl2 = WFv[768 + (2 * 4 + ch) * 64 + l];
                acc0 = __builtin_amdgcn_mfma_f32_16x16x32_bf16(ah, bh0, acc0, 0, 0, 0);
                acc0 = __builtin_amdgcn_mfma_f32_16x16x32_bf16(al, bh0, acc0, 0, 0, 0);
                acc0 = __builtin_amdgcn_mfma_f32_16x16x32_bf16(ah, bl0, acc0, 0, 0, 0);
                acc1 = __builtin_amdgcn_mfma_f32_16x16x32_bf16(ah, bh1, acc1, 0, 0, 0);
                acc1 = __builtin_amdgcn_mfma_f32_16x16x32_bf16(al, bh1, acc1, 0, 0, 0);
                acc1 = __builtin_amdgcn_mfma_f32_16x16x32_bf16(ah, bl1, acc1, 0, 0, 0);
                acc2 = __builtin_amdgcn_mfma_f32_16x16x32_bf16(ah, bh2, acc2, 0, 0, 0);
                acc2 = __builtin_amdgcn_mfma_f32_16x16x32_bf16(al, bh2, acc2, 0, 0, 0);
                acc2 = __builtin_amdgcn_mfma_f32_16x16x32_bf16(ah, bl2, acc2, 0, 0, 0);
            }
            int nlb = wid * 16 + 4 * lg;
            #pragma unroll
            for (int r = 0; r < 4; ++r) {
                int nd = mbase + 4 * lg + r;
                float di = (nd < N) ? dinv[nd] : 0.f;
                sm.ep[(nlb + r) * EPS + 0 * 16 + lr] = acc0[r] * di;
                sm.ep[(nlb + r) * EPS + 1 * 16 + lr] = acc1[r] * di;
                sm.ep[(nlb + r) * EPS + 2 * 16 + lr] = acc2[r] * di;
            }
            __syncthreads();
            for (int i = t; i < 320; i += 256) {
                int nl2 = i / 5;
                int cg = i - nl2 * 5;
                int node = base64 + nl2;
                if (node < N) {
                    const float* p = &sm.ep[nl2 * EPS + cg * 8];
                    float4 v0 = *(const float4*)p;
                    float4 v1 = *(const float4*)(p + 4);
                    uint4 o;
                    o.x = pack2(v0.x, v0.y);
                    o.y = pack2(v0.z, v0.w);
                    o.z = pack2(v1.x, v1.y);
                    o.w = pack2(v1.z, v1.w);
                    Z0[(size_t)node * ZSTR + cg] = o;
                }
            }
        }
    }
    gsync(ctr, 5 * GRID);

    // ---- P5: prop hop 1 (grid-stride) ----
    int pgrid = (N + NPB - 1) / NPB;
    for (int pb = bid; pb < pgrid; pb += GRID) {
        __syncthreads();   // LDS pr/red reuse across iterations
        prop_body<false>(sm, pb, rowptr, col, dinv, dsq, bias, Z0, Zb, nullptr, N);
    }
    gsync(ctr, 6 * GRID);

    // ---- P6: prop hop 2 + fused log_softmax ----
    for (int pb = bid; pb < pgrid; pb += GRID) {
        __syncthreads();
        prop_body<true>(sm, pb, rowptr, col, dinv, dsq, bias, Zb, nullptr, out, N);
    }
}

extern "C" void kernel_launch(void* const* d_in, const int* in_sizes, int n_in,
                              void* d_out, int out_size, void* d_ws, size_t ws_size,
                              hipStream_t stream) {
    const float* x = (const float*)d_in[0];
    const float* W = (const float*)d_in[1];
    const float* b = (const float*)d_in[2];
    const int* ei = (const int*)d_in[3];

    int C = in_sizes[2];            // 40
    int F = in_sizes[1] / C;        // 128
    int N = in_sizes[0] / F;        // 100000
    int E = in_sizes[3] / 2;        // 1600000
    const int* src = ei;
    const int* dst = ei + E;

    // workspace: union region {G,T,tmp} overlaid by Z0 (12.8MB) -- T/tmp are
    // consumed in P2/P3, Z0 written in P4 (after gsync). Zb, WF, ctr separate.
    char* ws = (char*)d_ws;
    size_t goff = 0;
    int* G = (int*)(ws + goff);                       goff += (size_t)NBLK * NB * 4;
    int* T = (int*)(ws + goff);                       goff += (size_t)NB * 4;
    goff = (goff + 15) & ~(size_t)15;
    unsigned int* tmp = (unsigned int*)(ws + goff);   goff += (size_t)E * 4;
    size_t z0bytes = (size_t)N * ZSTR * 16;           // 128 B per node
    size_t unionEnd = (z0bytes > goff) ? z0bytes : goff;
    unionEnd = (unionEnd + 15) & ~(size_t)15;
    uint4* Z0 = (uint4*)ws;          // overlays build scratch
    size_t off = unionEnd;
    int* rowptr = (int*)(ws + off); off += ((size_t)(N + 1) * 4 + 15) & ~(size_t)15;
    float* dinv = (float*)(ws + off); off += ((size_t)N * 4 + 15) & ~(size_t)15;
    float* dsq = (float*)(ws + off); off += ((size_t)N * 4 + 15) & ~(size_t)15;
    int* col = (int*)(ws + off); off += ((size_t)E * 4 + 15) & ~(size_t)15;
    uint4* Zb = (uint4*)(ws + off); off += (z0bytes + 15) & ~(size_t)15;
    uint4* WF = (uint4*)(ws + off); off += (size_t)2 * 768 * 16;
    int* ctr = (int*)(ws + off); off += 16;

    int EB = (E + NBLK - 1) / NBLK;

    hipMemsetAsync(ctr, 0, 4, stream);
    fused_k<<<GRID, 256, 0, stream>>>(src, dst, x, W, b, G, T, tmp,
                                      rowptr, dinv, dsq, col, WF,
                                      Z0, Zb, (float*)d_out, ctr, N, E, EB);
}

// Round 11
// 211.067 us; speedup vs baseline: 7.0779x; 7.0779x over previous
//
#include <hip/hip_runtime.h>
#include <math.h>

// SGC: out = log_softmax((A_hat^2 x) W + b), A_hat = D^-1/2 (A+I) D^-1/2
// (A^2 X) W == A^2 (X W): propagate in 40-dim class space.
// Z buffers bf16, 128B-padded rows; MFMA split-bf16 gemm; 2-team pull prop
// (8-wide software-pipelined gathers).
// Round-19: REVERT to round-17 state (211.96us, session best). Round-18's
// single-dispatch fusion regressed 7x (1494us): spin-wait grid barrier --
// ~1000 waves polling one device-scope line starve working blocks' memory
// traffic through the same L2/fabric queues (occupancy 49% co-resident,
// VALUBusy 2.5%, HBM 222GB/s dribble); also fused regalloc (52 VGPR)
// serialized prop's 8-deep gather pipeline. Boundaries-are-the-bottleneck
// is now twice-falsified (round-13 +10us, round-18 +1282us). This split
// 7-launch pipeline is the measured optimum; prop sits at its request/
// latency floor (4 consecutive MLP deepenings gained <2% each).

#define FDIM 128
#define CDIM 40
#define BKT_SHIFT 8
#define NB   512   // bucket slots (>= ceil(N/256))
#define NBLK 512   // edge-partition blocks
#define NPB  25    // nodes per 256-thread prop block (10 lanes/node, 2 teams)
#define ZSTR 8     // Z row stride in uint4 (128 B; 5 used, 3 pad)

typedef __attribute__((ext_vector_type(4))) float floatx4;
typedef __attribute__((ext_vector_type(8))) short bshort8;

// ---------- bf16 helpers (RTNE pack; finite inputs) ----------
__device__ __forceinline__ unsigned int bf16rn(float f) {
    unsigned int u = __float_as_uint(f);
    return (u + 0x7fffu + ((u >> 16) & 1u)) >> 16;
}
__device__ __forceinline__ unsigned int pack2(float lo, float hi) {
    unsigned int a = bf16rn(lo);
    unsigned int b = __float_as_uint(hi);
    b = (b + 0x7fffu + ((b >> 16) & 1u)) & 0xffff0000u;
    return a | b;
}
__device__ __forceinline__ void addu4(uint4 u, float* a) {
    a[0] += __uint_as_float(u.x << 16);
    a[1] += __uint_as_float(u.x & 0xffff0000u);
    a[2] += __uint_as_float(u.y << 16);
    a[3] += __uint_as_float(u.y & 0xffff0000u);
    a[4] += __uint_as_float(u.z << 16);
    a[5] += __uint_as_float(u.z & 0xffff0000u);
    a[6] += __uint_as_float(u.w << 16);
    a[7] += __uint_as_float(u.w & 0xffff0000u);
}

// ---- pass 1: per-block histogram over dst buckets (LDS, no global atomics).
// Block NBLK rides along as the W fragment prep (split-bf16, MFMA B order).
__global__ void hist_k(const int* __restrict__ dst, int* __restrict__ G,
                       int E, int EB, const float* __restrict__ W,
                       uint4* __restrict__ WF) {
    int t = threadIdx.x;
    if (blockIdx.x == NBLK) {
        // wprep: B frag for mfma_f32_16x16x32_bf16: lane l holds
        // B[k = 8*(l>>4)+j][n = l&15]; g = nt*4+ch; hi at WF[g*64+l],
        // lo at WF[768+g*64+l]. k_global = ch*32+8*(l>>4)+j.
        for (int s = t; s < 768; s += 256) {
            int l = s & 63;
            int g = s >> 6;
            int nt = g >> 2;
            int ch = g & 3;
            int c = nt * 16 + (l & 15);
            int kb = ch * 32 + ((l >> 4) << 3);
            unsigned int hw[4], lw[4];
            #pragma unroll
            for (int jw = 0; jw < 4; ++jw) {
                unsigned int hs[2], ls[2];
                #pragma unroll
                for (int e = 0; e < 2; ++e) {
                    int j = jw * 2 + e;
                    float w = (c < CDIM) ? W[(kb + j) * CDIM + c] : 0.f;
                    unsigned int u = __float_as_uint(w);
                    float wh = __uint_as_float(u & 0xffff0000u);
                    float wr = w - wh;
                    hs[e] = u >> 16;
                    ls[e] = __float_as_uint(wr) >> 16;
                }
                hw[jw] = hs[0] | (hs[1] << 16);
                lw[jw] = ls[0] | (ls[1] << 16);
            }
            WF[g * 64 + l] = make_uint4(hw[0], hw[1], hw[2], hw[3]);
            WF[768 + g * 64 + l] = make_uint4(lw[0], lw[1], lw[2], lw[3]);
        }
        return;
    }
    __shared__ int h[NB];
    for (int i = t; i < NB; i += 256) h[i] = 0;
    __syncthreads();
    int s = blockIdx.x * EB;
    int e = min(s + EB, E);
    for (int i = s + t; i < e; i += 256)
        atomicAdd(&h[dst[i] >> BKT_SHIFT], 1);
    __syncthreads();
    for (int i = t; i < NB; i += 256) G[blockIdx.x * NB + i] = h[i];
}

// ---- pass 2: per-bucket exclusive scan over blocks (in-place on G); totals->T
__global__ void colscan_k(int* __restrict__ G, int* __restrict__ T) {
    __shared__ int lds[256];
    int j = blockIdx.x;
    int t = threadIdx.x;
    int v0 = G[(2 * t) * NB + j];
    int v1 = G[(2 * t + 1) * NB + j];
    int s = v0 + v1;
    lds[t] = s;
    __syncthreads();
    for (int off = 1; off < 256; off <<= 1) {
        int a = (t >= off) ? lds[t - off] : 0;
        __syncthreads();
        lds[t] += a;
        __syncthreads();
    }
    int excl = lds[t] - s;
    G[(2 * t) * NB + j] = excl;
    G[(2 * t + 1) * NB + j] = excl + v0;
    if (t == 255) T[j] = lds[255];
}

// ---- inline exclusive scan of T[0..NB) into bsl[0..NB] (bsl[NB]=total).
__device__ __forceinline__ void scanT(const int* __restrict__ T, int* bsl,
                                      int* lds, int t) {
    int v0 = T[2 * t];
    int v1 = T[2 * t + 1];
    int s = v0 + v1;
    lds[t] = s;
    __syncthreads();
    for (int off = 1; off < 256; off <<= 1) {
        int a = (t >= off) ? lds[t - off] : 0;
        __syncthreads();
        lds[t] += a;
        __syncthreads();
    }
    int excl = lds[t] - s;
    bsl[2 * t] = excl;
    bsl[2 * t + 1] = excl + v0;
    if (t == 255) bsl[NB] = lds[255];
    __syncthreads();
}

// ---- pass 3: scatter packed edges into bucket-partitioned tmp
// pack: src (24 bits) | dstLocal (8 bits) << 24   [requires N < 2^24]
__global__ void part_k(const int* __restrict__ src, const int* __restrict__ dst,
                       const int* __restrict__ G, const int* __restrict__ T,
                       unsigned int* __restrict__ tmp, int E, int EB) {
    __shared__ int bsl[NB + 1];
    __shared__ int lds[256];
    __shared__ int offs[NB];
    __shared__ int cur[NB];
    int t = threadIdx.x;
    scanT(T, bsl, lds, t);
    for (int i = t; i < NB; i += 256) {
        offs[i] = bsl[i] + G[blockIdx.x * NB + i];
        cur[i] = 0;
    }
    __syncthreads();
    int s = blockIdx.x * EB;
    int e = min(s + EB, E);
    for (int i = s + t; i < e; i += 256) {
        int d = dst[i];
        int j = d >> BKT_SHIFT;
        int r = atomicAdd(&cur[j], 1);
        tmp[offs[j] + r] = (unsigned int)src[i] | ((unsigned int)(d & 255) << 24);
    }
}

// ---- pass 4: one block per bucket: rowptr/dinv/dsq + CSR col fill (all local)
__global__ void csr_k(const unsigned int* __restrict__ tmp, const int* __restrict__ T,
                      int* __restrict__ rowptr, float* __restrict__ dinv,
                      float* __restrict__ dsq, int* __restrict__ col, int N, int E) {
    __shared__ int bsl[NB + 1];
    __shared__ int lds[256];
    __shared__ int cnt[256];
    __shared__ int ptr[256];
    int j = blockIdx.x;
    int t = threadIdx.x;
    scanT(T, bsl, lds, t);
    int base = j << BKT_SHIFT;
    int s = bsl[j];
    int e = bsl[j + 1];
    cnt[t] = 0;
    __syncthreads();
    for (int i = s + t; i < e; i += 256)
        atomicAdd(&cnt[tmp[i] >> 24], 1);
    __syncthreads();
    int v = cnt[t];
    ptr[t] = v;
    __syncthreads();
    for (int off = 1; off < 256; off <<= 1) {
        int a = (t >= off) ? ptr[t - off] : 0;
        __syncthreads();
        ptr[t] += a;
        __syncthreads();
    }
    int excl = ptr[t] - v;
    int node = base + t;
    if (node < N) {
        rowptr[node] = s + excl;
        float d = (float)(v + 1);              // +1 self-loop
        dinv[node] = rsqrtf(d);
        dsq[node] = sqrtf(d);
    }
    if (j == 0 && t == 0) rowptr[N] = E;
    cnt[t] = excl;  // cursor
    __syncthreads();
    for (int i = s + t; i < e; i += 256) {
        unsigned int p = tmp[i];
        int loc = p >> 24;
        int r = atomicAdd(&cnt[loc], 1);
        col[s + r] = (int)(p & 0xFFFFFF);
    }
}

// ---- Z0[node][40] (bf16) = dinv[node] * (x[node] @ W)  -- MFMA.
// Wave = 16 nodes x 40 classes (3 N-tiles of 16). A frag (lane l: row l&15,
// k=8*(l>>4)+j) loads straight from global x (16 rows x 64B contiguous per
// instr). 3 MFMAs per (nt,ch): xh*Wh + xl*Wh + xh*Wl (split-bf16, rel err
// ~2^-15). Epilogue transposes D frags through 13KB LDS into 128B rows.
__device__ __forceinline__ void split8(const float* p, bshort8& hi, bshort8& lo) {
    float4 a = *(const float4*)p;
    float4 b = *(const float4*)(p + 4);
    float f[8] = {a.x, a.y, a.z, a.w, b.x, b.y, b.z, b.w};
    #pragma unroll
    for (int j = 0; j < 8; ++j) {
        unsigned int u = __float_as_uint(f[j]);
        float r = f[j] - __uint_as_float(u & 0xffff0000u);
        hi[j] = (short)(u >> 16);
        lo[j] = (short)(__float_as_uint(r) >> 16);
    }
}

#define EPS 52   // epilogue LDS row stride (floats)

__global__ __launch_bounds__(256) void gemm_k(const float* __restrict__ x,
                                              const uint4* __restrict__ WF,
                                              const float* __restrict__ dinv,
                                              uint4* __restrict__ Zbf, int n) {
    __shared__ float ep[64 * EPS];   // 13.3 KB
    int t = threadIdx.x;
    int wid = t >> 6;
    int l = t & 63;
    int lr = l & 15;
    int lg = l >> 4;
    int base64 = blockIdx.x * 64;
    int mbase = base64 + wid * 16;
    int node_a = mbase + lr;
    bool arow_ok = node_a < n;
    const bshort8* WFv = (const bshort8*)WF;

    floatx4 acc0 = {0.f, 0.f, 0.f, 0.f};
    floatx4 acc1 = {0.f, 0.f, 0.f, 0.f};
    floatx4 acc2 = {0.f, 0.f, 0.f, 0.f};

    #pragma unroll
    for (int ch = 0; ch < 4; ++ch) {
        bshort8 ah, al;
        if (arow_ok) {
            split8(x + (size_t)node_a * FDIM + ch * 32 + lg * 8, ah, al);
        } else {
            #pragma unroll
            for (int j = 0; j < 8; ++j) { ah[j] = 0; al[j] = 0; }
        }
        bshort8 bh0 = WFv[(0 * 4 + ch) * 64 + l];
        bshort8 bl0 = WFv[768 + (0 * 4 + ch) * 64 + l];
        bshort8 bh1 = WFv[(1 * 4 + ch) * 64 + l];
        bshort8 bl1 = WFv[768 + (1 * 4 + ch) * 64 + l];
        bshort8 bh2 = WFv[(2 * 4 + ch) * 64 + l];
        bshort8 bl2 = WFv[768 + (2 * 4 + ch) * 64 + l];
        acc0 = __builtin_amdgcn_mfma_f32_16x16x32_bf16(ah, bh0, acc0, 0, 0, 0);
        acc0 = __builtin_amdgcn_mfma_f32_16x16x32_bf16(al, bh0, acc0, 0, 0, 0);
        acc0 = __builtin_amdgcn_mfma_f32_16x16x32_bf16(ah, bl0, acc0, 0, 0, 0);
        acc1 = __builtin_amdgcn_mfma_f32_16x16x32_bf16(ah, bh1, acc1, 0, 0, 0);
        acc1 = __builtin_amdgcn_mfma_f32_16x16x32_bf16(al, bh1, acc1, 0, 0, 0);
        acc1 = __builtin_amdgcn_mfma_f32_16x16x32_bf16(ah, bl1, acc1, 0, 0, 0);
        acc2 = __builtin_amdgcn_mfma_f32_16x16x32_bf16(ah, bh2, acc2, 0, 0, 0);
        acc2 = __builtin_amdgcn_mfma_f32_16x16x32_bf16(al, bh2, acc2, 0, 0, 0);
        acc2 = __builtin_amdgcn_mfma_f32_16x16x32_bf16(ah, bl2, acc2, 0, 0, 0);
    }

    // epilogue: D lane l reg r -> node mbase + 4*lg + r, class nt*16 + lr.
    int nlb = wid * 16 + 4 * lg;
    #pragma unroll
    for (int r = 0; r < 4; ++r) {
        int nd = mbase + 4 * lg + r;
        float di = (nd < n) ? dinv[nd] : 0.f;
        ep[(nlb + r) * EPS + 0 * 16 + lr] = acc0[r] * di;
        ep[(nlb + r) * EPS + 1 * 16 + lr] = acc1[r] * di;
        ep[(nlb + r) * EPS + 2 * 16 + lr] = acc2[r] * di;
    }
    __syncthreads();
    for (int i = t; i < 320; i += 256) {
        int nl2 = i / 5;
        int cg = i - nl2 * 5;
        int node = base64 + nl2;
        if (node < n) {
            const float* p = &ep[nl2 * EPS + cg * 8];
            float4 v0 = *(const float4*)p;
            float4 v1 = *(const float4*)(p + 4);
            uint4 o;
            o.x = pack2(v0.x, v0.y);
            o.y = pack2(v0.z, v0.w);
            o.z = pack2(v1.x, v1.y);
            o.w = pack2(v1.z, v1.w);
            Zbf[(size_t)node * ZSTR + cg] = o;
        }
    }
}

// ---- one hop: acc = sum_{s->i} Zin[s] + Zin[i]; Zout = di^2 * acc.
// FINAL: fuse logits = Z2*dsq + b and log_softmax, write fp32 d_out.
// 10 lanes/node = 2 teams x 5 c8-lanes; 8 edges/iter/team; col loads
// software-pipelined (preload 8, prefetch next-8 between gather issue and
// accumulate). Guarded preload avoids deg-0 OOB.
template <bool FINAL>
__global__ __launch_bounds__(256) void prop_k(const int* __restrict__ rowptr,
                                              const int* __restrict__ col,
                                              const float* __restrict__ dinv,
                                              const float* __restrict__ dsq,
                                              const float* __restrict__ bias,
                                              const uint4* __restrict__ Zin,
                                              uint4* __restrict__ Zout_bf,
                                              float* __restrict__ out_f32, int n) {
    __shared__ float bsm[CDIM];
    __shared__ float red[256];
    __shared__ float pr[NPB * 5 * 8];   // team-1 partials, 4 KB
    int t = threadIdx.x;
    if (FINAL && t < CDIM) bsm[t] = bias[t];
    int g = t / 10;
    int r = t - g * 10;
    int team = r / 5;           // 0 or 1
    int c8 = r - team * 5;      // 0..4
    int node = blockIdx.x * NPB + g;
    bool active = (g < NPB) && (node < n);
    float acc[8];
    #pragma unroll
    for (int c = 0; c < 8; ++c) acc[c] = 0.f;
    float w = 0.f;
    if (active) {
        float di = dinv[node];
        w = di * di;
        if (team == 0) addu4(Zin[(size_t)node * ZSTR + c8], acc);   // self-loop
        int end = rowptr[node + 1];
        int end1 = end - 1;
        int e0 = rowptr[node] + team * 8;
        if (e0 < end) {
            int sv[8];
            #pragma unroll
            for (int k = 0; k < 8; ++k)
                sv[k] = col[min(e0 + k, end1)];     // preload iter 0
            for (int base = e0; base < end; base += 16) {
                uint4 av[8];
                #pragma unroll
                for (int k = 0; k < 8; ++k)
                    av[k] = Zin[(size_t)sv[k] * ZSTR + c8];  // 8 gathers in flight
                #pragma unroll
                for (int k = 0; k < 8; ++k)
                    sv[k] = col[min(base + 16 + k, end1)];   // prefetch iter+1
                #pragma unroll
                for (int k = 0; k < 8; ++k) {
                    if (base + k >= end) av[k] = make_uint4(0u, 0u, 0u, 0u);
                    addu4(av[k], acc);
                }
            }
        }
    }

    // merge team-1 partials into team-0 accumulators.
    if (active && team == 1) {
        float* p = &pr[(g * 5 + c8) * 8];
        #pragma unroll
        for (int j = 0; j < 8; ++j) p[j] = acc[j];
    }
    __syncthreads();   // also publishes bsm for FINAL
    if (active && team == 0) {
        const float* p = &pr[(g * 5 + c8) * 8];
        #pragma unroll
        for (int j = 0; j < 8; ++j) acc[j] += p[j];
    }

    if (!FINAL) {
        if (active && team == 0) {
            uint4 o;
            o.x = pack2(acc[0] * w, acc[1] * w);
            o.y = pack2(acc[2] * w, acc[3] * w);
            o.z = pack2(acc[4] * w, acc[5] * w);
            o.w = pack2(acc[6] * w, acc[7] * w);
            Zout_bf[(size_t)node * ZSTR + c8] = o;
        }
        return;
    }

    // FINAL: logits + log_softmax; reduce over the 5 team-0 lanes/node.
    float v[8];
    float m8 = -INFINITY;
    if (active && team == 0) {
        float ws_ = w * dsq[node];
        #pragma unroll
        for (int j = 0; j < 8; ++j) {
            v[j] = acc[j] * ws_ + bsm[c8 * 8 + j];
            m8 = fmaxf(m8, v[j]);
        }
    }
    red[t] = m8;
    __syncthreads();
    float m = m8;
    if (active && team == 0) {
        int rb = g * 10;
        m = fmaxf(fmaxf(fmaxf(red[rb], red[rb + 1]), fmaxf(red[rb + 2], red[rb + 3])),
                  red[rb + 4]);
    }
    float s8 = 0.f;
    if (active && team == 0) {
        #pragma unroll
        for (int j = 0; j < 8; ++j) s8 += expf(v[j] - m);
    }
    __syncthreads();
    red[t] = s8;
    __syncthreads();
    if (active && team == 0) {
        int rb = g * 10;
        float s = (red[rb] + red[rb + 1]) + (red[rb + 2] + red[rb + 3]) + red[rb + 4];
        float ls = m + logf(s);
        float* p = out_f32 + (size_t)node * CDIM + c8 * 8;
        *(float4*)p = make_float4(v[0] - ls, v[1] - ls, v[2] - ls, v[3] - ls);
        *(float4*)(p + 4) = make_float4(v[4] - ls, v[5] - ls, v[6] - ls, v[7] - ls);
    }
}

extern "C" void kernel_launch(void* const* d_in, const int* in_sizes, int n_in,
                              void* d_out, int out_size, void* d_ws, size_t ws_size,
                              hipStream_t stream) {
    const float* x = (const float*)d_in[0];
    const float* W = (const float*)d_in[1];
    const float* b = (const float*)d_in[2];
    const int* ei = (const int*)d_in[3];

    int C = in_sizes[2];            // 40
    int F = in_sizes[1] / C;        // 128
    int N = in_sizes[0] / F;        // 100000
    int E = in_sizes[3] / 2;        // 1600000
    const int* src = ei;
    const int* dst = ei + E;

    // workspace: union region holds {G,T,tmp} during build, then Z0bf
    // (12.8MB, 128B rows). Zb separate (hop-2 gathers from it while writing
    // d_out). WF separate (written by hist_k block NBLK, read by gemm_k).
    char* ws = (char*)d_ws;
    size_t goff = 0;
    int* G = (int*)(ws + goff);                       goff += (size_t)NBLK * NB * 4;
    int* T = (int*)(ws + goff);                       goff += (size_t)NB * 4;
    goff = (goff + 15) & ~(size_t)15;
    unsigned int* tmp = (unsigned int*)(ws + goff);   goff += (size_t)E * 4;
    size_t z0bytes = (size_t)N * ZSTR * 16;           // 128 B per node
    size_t unionEnd = (z0bytes > goff) ? z0bytes : goff;
    unionEnd = (unionEnd + 15) & ~(size_t)15;
    uint4* Z0bf = (uint4*)ws;        // overlays build scratch
    size_t off = unionEnd;
    int* rowptr = (int*)(ws + off); off += ((size_t)(N + 1) * 4 + 15) & ~(size_t)15;
    float* dinv = (float*)(ws + off); off += ((size_t)N * 4 + 15) & ~(size_t)15;
    float* dsq = (float*)(ws + off); off += ((size_t)N * 4 + 15) & ~(size_t)15;
    int* col = (int*)(ws + off); off += ((size_t)E * 4 + 15) & ~(size_t)15;
    uint4* Zb = (uint4*)(ws + off); off += (z0bytes + 15) & ~(size_t)15;
    uint4* WF = (uint4*)(ws + off); off += (size_t)2 * 768 * 16;

    // T is consumed by part_k and csr_k, both before gemm_k overwrites the
    // union region with Z0bf. Safe.

    int EB = (E + NBLK - 1) / NBLK;
    int NBr = (N + 255) >> BKT_SHIFT;

    hist_k<<<NBLK + 1, 256, 0, stream>>>(dst, G, E, EB, W, WF);
    colscan_k<<<NB, 256, 0, stream>>>(G, T);
    part_k<<<NBLK, 256, 0, stream>>>(src, dst, G, T, tmp, E, EB);
    csr_k<<<NBr, 256, 0, stream>>>(tmp, T, rowptr, dinv, dsq, col, N, E);

    gemm_k<<<(N + 63) / 64, 256, 0, stream>>>(x, WF, dinv, Z0bf, N);

    int pgrid = (N + NPB - 1) / NPB;
    prop_k<false><<<pgrid, 256, 0, stream>>>(rowptr, col, dinv, dsq, b,
                                             Z0bf, Zb, nullptr, N);
    prop_k<true><<<pgrid, 256, 0, stream>>>(rowptr, col, dinv, dsq, b,
                                            Zb, nullptr, (float*)d_out, N);
}